// Round 3
// baseline (419.470 us; speedup 1.0000x reference)
//
#include <hip/hip_runtime.h>

#define BATCH 262144
#define EMB 300
#define VOC 100000
#define NBLK 4096
#define WPB 4
// 16 lanes per pair, 4 pair-groups per wave, 4 steps => 16 pairs/wave
// NBLK * WPB * 16 == BATCH

// ---- locality sort parameters ----
#define BSHIFT 7
#define NBUCKET ((VOC + (1 << BSHIFT) - 1) >> BSHIFT)   // 782 buckets of 128 rows

// ---- workspace layout (bytes) ----
#define WS_BLOCKSUMS 0                        // 4096 floats = 16 KB
#define WS_HIST      16384                    // 1024 ints (782 used)
#define WS_OFFS      20480                    // 1024 ints
#define WS_SC        24576                    // BATCH ints   (sorted center)
#define WS_SO        (WS_SC  + 1048576)       // BATCH ints   (sorted outside)
#define WS_SCC       (WS_SO  + 1048576)       // BATCH floats (sorted coocs)
#define WS_SWT       (WS_SCC + 1048576)       // BATCH floats (sorted weighting)
#define WS_SID       (WS_SWT + 1048576)       // BATCH ints   (orig pair id)
#define WS_PLOSS     (WS_SID + 1048576)       // BATCH floats (per-pair loss)
#define WS_NEED      (WS_PLOSS + 1048576)     // ~6.02 MB + 24 KB

// ------------------------------------------------------------------
// Sort pass 1: bucket histogram
// ------------------------------------------------------------------
__global__ __launch_bounds__(256) void glove_hist(
    const int* __restrict__ center, int* __restrict__ hist)
{
    const int i = blockIdx.x * 256 + threadIdx.x;
    atomicAdd(&hist[center[i] >> BSHIFT], 1);
}

// ------------------------------------------------------------------
// Sort pass 2: exclusive scan of 782 bucket counts (single block)
// (functionally verified in round 1: pipeline passed with absmax 0)
// ------------------------------------------------------------------
__global__ __launch_bounds__(1024) void glove_scan(
    const int* __restrict__ hist, int* __restrict__ offs)
{
    const int t = threadIdx.x;
    int v = (t < NBUCKET) ? hist[t] : 0;
    const int orig = v;

    #pragma unroll
    for (int off = 1; off < 64; off <<= 1) {
        int n = __shfl_up(v, off, 64);
        if ((t & 63) >= off) v += n;
    }
    __shared__ int wsums[16];
    if ((t & 63) == 63) wsums[t >> 6] = v;
    __syncthreads();
    if (t < 16) {
        int w = wsums[t];
        #pragma unroll
        for (int off = 1; off < 16; off <<= 1) {
            int n = __shfl_up(w, off, 16);
            if (t >= off) w += n;
        }
        wsums[t] = w;
    }
    __syncthreads();
    const int add = (t >= 64) ? wsums[(t >> 6) - 1] : 0;
    if (t < NBUCKET) offs[t] = (v + add) - orig;   // exclusive prefix
}

// ------------------------------------------------------------------
// Sort pass 3: scatter PACKED pair records into bucket order.
// Slot races within a bucket are harmless: per-pair values are
// order-independent and the final sum re-reads by original id.
// ------------------------------------------------------------------
__global__ __launch_bounds__(256) void glove_scatter(
    const int*   __restrict__ center,
    const int*   __restrict__ outside,
    const float* __restrict__ coocs,
    const float* __restrict__ weighting,
    int* __restrict__ offs,
    int* __restrict__ sc, int* __restrict__ so,
    float* __restrict__ scc, float* __restrict__ swt,
    int* __restrict__ sid)
{
    const int i = blockIdx.x * 256 + threadIdx.x;
    const int c = center[i];
    const int slot = atomicAdd(&offs[c >> BSHIFT], 1);
    sc[slot]  = c;
    so[slot]  = outside[i];
    scc[slot] = coocs[i];
    swt[slot] = weighting[i];
    sid[slot] = i;
}

// ------------------------------------------------------------------
// Main gather+dot kernel over bucket-sorted pairs, XCD-pinned sweep:
// chunk = (bid&7)*512 + (bid>>3)  -> HW XCD (bid%8) sweeps its own
// contiguous 1/8 of the sorted order => center rows stay L2-resident.
// Inner arithmetic is verbatim from the verified baseline kernel.
// ------------------------------------------------------------------
__global__ __launch_bounds__(256) void glove_main_sorted(
    const int*   __restrict__ sc,
    const int*   __restrict__ so,
    const float* __restrict__ scc_in,
    const float* __restrict__ swt_in,
    const int*   __restrict__ sid,
    const float* __restrict__ cemb,
    const float* __restrict__ oemb,
    const float* __restrict__ cbias,
    const float* __restrict__ obias,
    float*       __restrict__ pair_loss)
{
    const int tid  = threadIdx.x;
    const int warp = tid >> 6;
    const int lane = tid & 63;
    const int l    = lane & 15;   // lane within 16-lane pair-group
    const int g    = lane >> 4;   // pair-group 0..3
    const int bid  = blockIdx.x;
    const int chunk = ((bid & 7) << 9) + (bid >> 3);   // XCD-pinned sweep
    const int base  = chunk * 64 + warp * 16 + g;      // slot of stage 0

    int ci[4], oi[4], id[4];
    #pragma unroll
    for (int it = 0; it < 4; ++it) {
        ci[it] = sc[base + it * 4];
        oi[it] = so[base + it * 4];
        id[it] = sid[base + it * 4];
    }

    // double-buffered stage registers (baseline-verbatim structure)
    float4 sa[2][5], sb[2][5];
    float  scb[2], sob[2], scc[2], swt[2];

    // ---- prologue: load stages 0 and 1 ----
    #pragma unroll
    for (int s = 0; s < 2; ++s) {
        const float4* __restrict__ A = (const float4*)(cemb + (long)ci[s] * EMB);
        const float4* __restrict__ B = (const float4*)(oemb + (long)oi[s] * EMB);
        #pragma unroll
        for (int i = 0; i < 4; ++i) {
            sa[s][i] = A[i * 16 + l];
            sb[s][i] = B[i * 16 + l];
        }
        sa[s][4].x = 0.f; sa[s][4].y = 0.f; sa[s][4].z = 0.f; sa[s][4].w = 0.f;
        sb[s][4] = sa[s][4];
        if (l < 11) {               // 75 float4/row: lanes 0..10 cover [64,75)
            sa[s][4] = A[64 + l];
            sb[s][4] = B[64 + l];
        }
        scb[s] = cbias[ci[s]];
        sob[s] = obias[oi[s]];
        scc[s] = scc_in[base + s * 4];
        swt[s] = swt_in[base + s * 4];
    }

    // ---- pipelined main: compute stage it from buf, refill buf with it+2 ----
    #pragma unroll
    for (int it = 0; it < 4; ++it) {
        const int buf = it & 1;

        float s = 0.f;
        #pragma unroll
        for (int i = 0; i < 5; ++i) {
            s += sa[buf][i].x * sb[buf][i].x + sa[buf][i].y * sb[buf][i].y
               + sa[buf][i].z * sb[buf][i].z + sa[buf][i].w * sb[buf][i].w;
        }
        const float cbv = scb[buf], obv = sob[buf], ccv = scc[buf], wtv = swt[buf];

        if (it + 2 < 4) {
            const int n = it + 2;
            const float4* __restrict__ A = (const float4*)(cemb + (long)ci[n] * EMB);
            const float4* __restrict__ B = (const float4*)(oemb + (long)oi[n] * EMB);
            #pragma unroll
            for (int i = 0; i < 4; ++i) {
                sa[buf][i] = A[i * 16 + l];
                sb[buf][i] = B[i * 16 + l];
            }
            if (l < 11) {
                sa[buf][4] = A[64 + l];
                sb[buf][4] = B[64 + l];
            } else {
                sa[buf][4].x = 0.f; sa[buf][4].y = 0.f; sa[buf][4].z = 0.f; sa[buf][4].w = 0.f;
                sb[buf][4] = sa[buf][4];
            }
            scb[buf] = cbias[ci[n]];
            sob[buf] = obias[oi[n]];
            scc[buf] = scc_in[base + n * 4];
            swt[buf] = swt_in[base + n * 4];
        }

        // 4-step butterfly within the 16-lane group
        s += __shfl_xor(s, 1);
        s += __shfl_xor(s, 2);
        s += __shfl_xor(s, 4);
        s += __shfl_xor(s, 8);

        if (l == 0) {
            const float e = s + cbv + obv - ccv;
            pair_loss[id[it]] = wtv * e * e;
        }
    }
}

// ------------------------------------------------------------------
// Exact-tree re-sum: block b's pairs are exactly pair_loss[b*64..+63]
// (base = (b*4+warp)*16+g, +it*4 covers [b*64,(b+1)*64)).
// One wave per output: coalesced 256-B read, then replay the baseline
// reduction tree bit-exactly via shuffles:
//   per (warp,g): ((v_it0+v_it1)+v_it2)+v_it3
//   per warp:     (g0+g2)+(g1+g3)
//   per block:    ((w0+w1)+w2)+w3
// ------------------------------------------------------------------
__global__ __launch_bounds__(256) void glove_sum_fast(
    const float* __restrict__ pair_loss, float* __restrict__ block_sums)
{
    const int tid  = threadIdx.x;
    const int lane = tid & 63;
    const int b    = blockIdx.x * 4 + (tid >> 6);   // wave id = output id

    const float v = pair_loss[b * 64 + lane];       // index = warp*16 + g + it*4

    float s = v;                                    // it-chain (lanes with it=0)
    s += __shfl(v, lane + 4, 64);
    s += __shfl(v, lane + 8, 64);
    s += __shfl(v, lane + 12, 64);

    float a = s + __shfl(s, lane + 2, 64);          // g0+g2 (lane r=0), g1+g3 (r=1)
    float y = a + __shfl(a, lane + 1, 64);          // (g0+g2)+(g1+g3) at r=0

    float t = y + __shfl(y, lane + 16, 64);         // w0+w1
    t += __shfl(y, lane + 32, 64);                  // +w2
    t += __shfl(y, lane + 48, 64);                  // +w3

    if (lane == 0) block_sums[b] = t;
}

// ------------------------------------------------------------------
// Baseline main kernel kept verbatim as fallback if ws is too small
// ------------------------------------------------------------------
__global__ __launch_bounds__(256) void glove_main(
    const int*   __restrict__ center,
    const int*   __restrict__ outside,
    const float* __restrict__ coocs,
    const float* __restrict__ weighting,
    const float* __restrict__ cemb,
    const float* __restrict__ oemb,
    const float* __restrict__ cbias,
    const float* __restrict__ obias,
    float*       __restrict__ block_sums)
{
    const int tid  = threadIdx.x;
    const int warp = tid >> 6;
    const int lane = tid & 63;
    const int l    = lane & 15;
    const int g    = lane >> 4;
    const int base = (blockIdx.x * WPB + warp) * 16 + g;

    int ci[4], oi[4];
    #pragma unroll
    for (int it = 0; it < 4; ++it) {
        ci[it] = center[base + it * 4];
        oi[it] = outside[base + it * 4];
    }

    float4 sa[2][5], sb[2][5];
    float  scb[2], sob[2], scc[2], swt[2];

    #pragma unroll
    for (int s = 0; s < 2; ++s) {
        const float4* __restrict__ A = (const float4*)(cemb + (long)ci[s] * EMB);
        const float4* __restrict__ B = (const float4*)(oemb + (long)oi[s] * EMB);
        #pragma unroll
        for (int i = 0; i < 4; ++i) {
            sa[s][i] = A[i * 16 + l];
            sb[s][i] = B[i * 16 + l];
        }
        sa[s][4].x = 0.f; sa[s][4].y = 0.f; sa[s][4].z = 0.f; sa[s][4].w = 0.f;
        sb[s][4] = sa[s][4];
        if (l < 11) {
            sa[s][4] = A[64 + l];
            sb[s][4] = B[64 + l];
        }
        scb[s] = cbias[ci[s]];
        sob[s] = obias[oi[s]];
        scc[s] = coocs[base + s * 4];
        swt[s] = weighting[base + s * 4];
    }

    float local = 0.0f;

    #pragma unroll
    for (int it = 0; it < 4; ++it) {
        const int buf = it & 1;

        float s = 0.f;
        #pragma unroll
        for (int i = 0; i < 5; ++i) {
            s += sa[buf][i].x * sb[buf][i].x + sa[buf][i].y * sb[buf][i].y
               + sa[buf][i].z * sb[buf][i].z + sa[buf][i].w * sb[buf][i].w;
        }
        const float cbv = scb[buf], obv = sob[buf], ccv = scc[buf], wtv = swt[buf];

        if (it + 2 < 4) {
            const int n = it + 2;
            const float4* __restrict__ A = (const float4*)(cemb + (long)ci[n] * EMB);
            const float4* __restrict__ B = (const float4*)(oemb + (long)oi[n] * EMB);
            #pragma unroll
            for (int i = 0; i < 4; ++i) {
                sa[buf][i] = A[i * 16 + l];
                sb[buf][i] = B[i * 16 + l];
            }
            if (l < 11) {
                sa[buf][4] = A[64 + l];
                sb[buf][4] = B[64 + l];
            } else {
                sa[buf][4].x = 0.f; sa[buf][4].y = 0.f; sa[buf][4].z = 0.f; sa[buf][4].w = 0.f;
                sb[buf][4] = sa[buf][4];
            }
            scb[buf] = cbias[ci[n]];
            sob[buf] = obias[oi[n]];
            scc[buf] = coocs[base + n * 4];
            swt[buf] = weighting[base + n * 4];
        }

        s += __shfl_xor(s, 1);
        s += __shfl_xor(s, 2);
        s += __shfl_xor(s, 4);
        s += __shfl_xor(s, 8);

        if (l == 0) {
            const float e = s + cbv + obv - ccv;
            local += wtv * e * e;
        }
    }

    local += __shfl_down(local, 32, 64);
    local += __shfl_down(local, 16, 64);

    __shared__ float smem[WPB];
    if (lane == 0) smem[warp] = local;
    __syncthreads();
    if (tid == 0)
        block_sums[blockIdx.x] = smem[0] + smem[1] + smem[2] + smem[3];
}

__global__ __launch_bounds__(1024) void glove_reduce(
    const float* __restrict__ part, float* __restrict__ out)
{
    const int t = threadIdx.x;
    float4 v = ((const float4*)part)[t];          // 1024 x 4 = 4096 partials
    float s = v.x + v.y + v.z + v.w;
    #pragma unroll
    for (int off = 32; off > 0; off >>= 1)
        s += __shfl_down(s, off, 64);
    __shared__ float sm[16];
    if ((t & 63) == 0) sm[t >> 6] = s;
    __syncthreads();
    if (t < 16) {
        float x = sm[t];
        #pragma unroll
        for (int off = 8; off > 0; off >>= 1)
            x += __shfl_down(x, off, 16);
        if (t == 0) out[0] = x;
    }
}

extern "C" void kernel_launch(void* const* d_in, const int* in_sizes, int n_in,
                              void* d_out, int out_size, void* d_ws, size_t ws_size,
                              hipStream_t stream) {
    const int*   center    = (const int*)  d_in[0];
    const int*   outside   = (const int*)  d_in[1];
    const float* coocs     = (const float*)d_in[2];
    const float* weighting = (const float*)d_in[3];
    const float* cemb      = (const float*)d_in[4];
    const float* oemb      = (const float*)d_in[5];
    const float* cbias     = (const float*)d_in[6];
    const float* obias     = (const float*)d_in[7];
    float* out = (float*)d_out;

    if (ws_size >= (size_t)WS_NEED) {
        char*  ws         = (char*)d_ws;
        float* block_sums = (float*)(ws + WS_BLOCKSUMS);
        int*   hist       = (int*)  (ws + WS_HIST);
        int*   offs       = (int*)  (ws + WS_OFFS);
        int*   sc         = (int*)  (ws + WS_SC);
        int*   so         = (int*)  (ws + WS_SO);
        float* scc        = (float*)(ws + WS_SCC);
        float* swt        = (float*)(ws + WS_SWT);
        int*   sid        = (int*)  (ws + WS_SID);
        float* ploss      = (float*)(ws + WS_PLOSS);

        hipMemsetAsync(hist, 0, 4096, stream);
        glove_hist   <<<BATCH / 256, 256, 0, stream>>>(center, hist);
        glove_scan   <<<1, 1024, 0, stream>>>(hist, offs);
        glove_scatter<<<BATCH / 256, 256, 0, stream>>>(
            center, outside, coocs, weighting, offs, sc, so, scc, swt, sid);
        glove_main_sorted<<<NBLK, 256, 0, stream>>>(
            sc, so, scc, swt, sid, cemb, oemb, cbias, obias, ploss);
        glove_sum_fast<<<NBLK / 4, 256, 0, stream>>>(ploss, block_sums);
        glove_reduce <<<1, 1024, 0, stream>>>(block_sums, out);
    } else {
        float* block_sums = (float*)d_ws;   // fallback: baseline path
        glove_main  <<<NBLK, 256, 0, stream>>>(
            center, outside, coocs, weighting, cemb, oemb, cbias, obias, block_sums);
        glove_reduce<<<1, 1024, 0, stream>>>(block_sums, out);
    }
}